// Round 1
// baseline (216.399 us; speedup 1.0000x reference)
//
#include <hip/hip_runtime.h>
#include <math.h>

// BioTripletLoss: B=16384 rows, D=1024 fp32.
// pos_dist[i] = ||h[i]+r[i]-t[i]||, neg_dist[i] = ||h[i]+r[i]-t[neg_idx[i]]||
// dissim (rel==1): relu(0.6 - pos) + 0.5*exp(-pos)
// sim:             relu(pos - neg + 0.3) + 0.3*relu(0.1 - pos)
// out = mean(per_sample)

#define BDIM 16384
#define DDIM 1024

// One wave (64 lanes) per row; 4 waves per block -> 4096 blocks.
// Per lane: 4 float4 loads per operand, float4-index = lane + 64*j (coalesced).
__global__ __launch_bounds__(256) void triplet_rows_kernel(
    const float* __restrict__ h, const float* __restrict__ t,
    const float* __restrict__ r, const int* __restrict__ rel,
    const int* __restrict__ neg, float* __restrict__ per_row)
{
    const int wave = threadIdx.x >> 6;
    const int lane = threadIdx.x & 63;
    const int row  = (blockIdx.x << 2) + wave;

    const float4* h4 = (const float4*)(h + (size_t)row * DDIM);
    const float4* t4 = (const float4*)(t + (size_t)row * DDIM);
    const float4* r4 = (const float4*)(r + (size_t)row * DDIM);
    const int nidx   = neg[row];
    const float4* n4 = (const float4*)(t + (size_t)nidx * DDIM);

    float psum = 0.0f, nsum = 0.0f;
#pragma unroll
    for (int j = 0; j < 4; ++j) {
        const int k = lane + (j << 6);   // float4 index 0..255
        float4 hv = h4[k];
        float4 rv = r4[k];
        float4 tv = t4[k];
        float4 nv = n4[k];
        float hrx = hv.x + rv.x, hry = hv.y + rv.y,
              hrz = hv.z + rv.z, hrw = hv.w + rv.w;
        float dx = hrx - tv.x, dy = hry - tv.y,
              dz = hrz - tv.z, dw = hrw - tv.w;
        psum += dx * dx + dy * dy + dz * dz + dw * dw;
        float ex = hrx - nv.x, ey = hry - nv.y,
              ez = hrz - nv.z, ew = hrw - nv.w;
        nsum += ex * ex + ey * ey + ez * ez + ew * ew;
    }

    // wave-64 butterfly reduction
#pragma unroll
    for (int off = 32; off > 0; off >>= 1) {
        psum += __shfl_down(psum, off, 64);
        nsum += __shfl_down(nsum, off, 64);
    }

    if (lane == 0) {
        float pos = sqrtf(psum);
        float negd = sqrtf(nsum);
        float loss;
        if (rel[row] == 1) {
            // curr_margin = MARGIN * PUSH_SCALE = 0.6
            loss = fmaxf(0.6f - pos, 0.0f) + 0.5f * expf(-pos);
        } else {
            loss = fmaxf(pos - negd + 0.3f, 0.0f)
                 + 0.3f * fmaxf(0.1f - pos, 0.0f);
        }
        per_row[row] = loss;
    }
}

// Single-block deterministic mean over the 16384 per-row losses.
__global__ __launch_bounds__(256) void reduce_mean_kernel(
    const float* __restrict__ per_row, float* __restrict__ out)
{
    __shared__ float sm[4];
    float s = 0.0f;
    for (int i = threadIdx.x; i < BDIM; i += 256)
        s += per_row[i];
#pragma unroll
    for (int off = 32; off > 0; off >>= 1)
        s += __shfl_down(s, off, 64);
    const int lane = threadIdx.x & 63;
    const int wave = threadIdx.x >> 6;
    if (lane == 0) sm[wave] = s;
    __syncthreads();
    if (threadIdx.x == 0)
        out[0] = (sm[0] + sm[1] + sm[2] + sm[3]) * (1.0f / (float)BDIM);
}

extern "C" void kernel_launch(void* const* d_in, const int* in_sizes, int n_in,
                              void* d_out, int out_size, void* d_ws, size_t ws_size,
                              hipStream_t stream) {
    const float* h = (const float*)d_in[0];
    const float* t = (const float*)d_in[1];
    const float* r = (const float*)d_in[2];
    const int* rel = (const int*)d_in[3];
    const int* neg = (const int*)d_in[4];
    float* per_row = (float*)d_ws;          // 16384 floats = 64 KB
    float* out = (float*)d_out;

    triplet_rows_kernel<<<BDIM / 4, 256, 0, stream>>>(h, t, r, rel, neg, per_row);
    reduce_mean_kernel<<<1, 256, 0, stream>>>(per_row, out);
}

// Round 2
// 207.265 us; speedup vs baseline: 1.0441x; 1.0441x over previous
//
#include <hip/hip_runtime.h>
#include <math.h>

// BioTripletLoss: B=16384 rows, D=1024 fp32.
// pos_dist[i] = ||h[i]+r[i]-t[i]||, neg_dist[i] = ||h[i]+r[i]-t[neg_idx[i]]||
// dissim (rel==1): relu(0.6 - pos) + 0.5*exp(-pos)
// sim:             relu(pos - neg + 0.3) + 0.3*relu(0.1 - pos)
// out = mean(per_sample)
//
// R2: 2 rows per wave (32 independent float4 loads in flight -> MLP),
//     fused final reduction via per-block atomicAdd, neg-row load aliased
//     to t-row for dissimilar rows (L1 hit instead of extra HBM gather).

#define BDIM 16384
#define DDIM 1024
#define NBLOCK 2048   // 4 waves/block, 2 rows/wave -> 16384 rows

__global__ void zero_out_kernel(float* __restrict__ out) { out[0] = 0.0f; }

__global__ __launch_bounds__(256) void triplet_fused_kernel(
    const float* __restrict__ h, const float* __restrict__ t,
    const float* __restrict__ r, const int* __restrict__ rel,
    const int* __restrict__ neg, float* __restrict__ out)
{
    const int wave = threadIdx.x >> 6;
    const int lane = threadIdx.x & 63;
    const int wid  = (blockIdx.x << 2) + wave;   // 0..8191
    const int row0 = wid << 1;
    const int row1 = row0 + 1;

    const float4* h0 = (const float4*)(h + (size_t)row0 * DDIM);
    const float4* r0 = (const float4*)(r + (size_t)row0 * DDIM);
    const float4* t0 = (const float4*)(t + (size_t)row0 * DDIM);
    const float4* h1 = (const float4*)(h + (size_t)row1 * DDIM);
    const float4* r1 = (const float4*)(r + (size_t)row1 * DDIM);
    const float4* t1 = (const float4*)(t + (size_t)row1 * DDIM);

    const int rel0 = rel[row0];
    const int rel1 = rel[row1];
    // dissimilar rows never use neg_dist: alias to t-row -> L1 hits, no branch
    const float4* n0 = (rel0 == 1) ? t0 : (const float4*)(t + (size_t)neg[row0] * DDIM);
    const float4* n1 = (rel1 == 1) ? t1 : (const float4*)(t + (size_t)neg[row1] * DDIM);

    float ps0 = 0.0f, ns0 = 0.0f, ps1 = 0.0f, ns1 = 0.0f;
#pragma unroll
    for (int j = 0; j < 4; ++j) {
        const int k = lane + (j << 6);   // float4 index 0..255
        float4 ha = h0[k]; float4 ra = r0[k]; float4 ta = t0[k]; float4 na = n0[k];
        float4 hb = h1[k]; float4 rb = r1[k]; float4 tb = t1[k]; float4 nb = n1[k];

        float ax = ha.x + ra.x, ay = ha.y + ra.y, az = ha.z + ra.z, aw = ha.w + ra.w;
        float dx = ax - ta.x, dy = ay - ta.y, dz = az - ta.z, dw = aw - ta.w;
        ps0 += dx * dx + dy * dy + dz * dz + dw * dw;
        float ex = ax - na.x, ey = ay - na.y, ez = az - na.z, ew = aw - na.w;
        ns0 += ex * ex + ey * ey + ez * ez + ew * ew;

        float bx = hb.x + rb.x, by = hb.y + rb.y, bz = hb.z + rb.z, bw = hb.w + rb.w;
        float fx = bx - tb.x, fy = by - tb.y, fz = bz - tb.z, fw = bw - tb.w;
        ps1 += fx * fx + fy * fy + fz * fz + fw * fw;
        float gx = bx - nb.x, gy = by - nb.y, gz = bz - nb.z, gw = bw - nb.w;
        ns1 += gx * gx + gy * gy + gz * gz + gw * gw;
    }

    // wave-64 butterfly reduction of all 4 partials (interleaved chains)
#pragma unroll
    for (int off = 32; off > 0; off >>= 1) {
        ps0 += __shfl_down(ps0, off, 64);
        ns0 += __shfl_down(ns0, off, 64);
        ps1 += __shfl_down(ps1, off, 64);
        ns1 += __shfl_down(ns1, off, 64);
    }

    __shared__ float sm[4];
    if (lane == 0) {
        float pos0 = sqrtf(ps0), neg0 = sqrtf(ns0);
        float pos1 = sqrtf(ps1), neg1 = sqrtf(ns1);
        float l0, l1;
        if (rel0 == 1) l0 = fmaxf(0.6f - pos0, 0.0f) + 0.5f * expf(-pos0);
        else           l0 = fmaxf(pos0 - neg0 + 0.3f, 0.0f) + 0.3f * fmaxf(0.1f - pos0, 0.0f);
        if (rel1 == 1) l1 = fmaxf(0.6f - pos1, 0.0f) + 0.5f * expf(-pos1);
        else           l1 = fmaxf(pos1 - neg1 + 0.3f, 0.0f) + 0.3f * fmaxf(0.1f - pos1, 0.0f);
        sm[wave] = l0 + l1;
    }
    __syncthreads();
    if (threadIdx.x == 0) {
        float blk = (sm[0] + sm[1] + sm[2] + sm[3]) * (1.0f / (float)BDIM);
        atomicAdd(out, blk);   // device-scope by default on CDNA
    }
}

extern "C" void kernel_launch(void* const* d_in, const int* in_sizes, int n_in,
                              void* d_out, int out_size, void* d_ws, size_t ws_size,
                              hipStream_t stream) {
    const float* h = (const float*)d_in[0];
    const float* t = (const float*)d_in[1];
    const float* r = (const float*)d_in[2];
    const int* rel = (const int*)d_in[3];
    const int* neg = (const int*)d_in[4];
    float* out = (float*)d_out;

    zero_out_kernel<<<1, 1, 0, stream>>>(out);
    triplet_fused_kernel<<<NBLOCK, 256, 0, stream>>>(h, t, r, rel, neg, out);
}